// Round 3
// baseline (585.088 us; speedup 1.0000x reference)
//
#include <hip/hip_runtime.h>
#include <hip/hip_bf16.h>
#include <cstdint>
#include <cstddef>

#define B_ROWS 16384
#define D_IN   512
#define D_HID  1024
#define D_MEM  1152
#define D_C    2688   // 512+1024+1152
#define D_HM   2176   // 1024+1152
#define N_U    224    // padded from 196

typedef __attribute__((ext_vector_type(8))) short bf16x8;
typedef __attribute__((ext_vector_type(4))) float f32x4;

static __device__ __forceinline__ unsigned short f2bf(float f) {
  unsigned u = __float_as_uint(f);
  unsigned r = u + 0x7fffu + ((u >> 16) & 1u);   // RNE
  return (unsigned short)(r >> 16);
}

#define GLOAD16(g, l) __builtin_amdgcn_global_load_lds( \
    (const __attribute__((address_space(1))) void*)(g), \
    (__attribute__((address_space(3))) void*)(l), 16, 0, 0)

// ---------------------------------------------------------------- weight conversions
__global__ void conv_w4(const float* __restrict__ W, unsigned short* __restrict__ o, int n4) {
  for (int i = blockIdx.x*blockDim.x + threadIdx.x; i < n4; i += gridDim.x*blockDim.x) {
    float4 v = ((const float4*)W)[i];
    ushort4 u; u.x=f2bf(v.x); u.y=f2bf(v.y); u.z=f2bf(v.z); u.w=f2bf(v.w);
    ((ushort4*)o)[i] = u;
  }
}

// Wcat rows: [0:96)=W_va, [96:192)=W_vb, [192:194)=W_a, [194:196)=W_b, [196:224)=0
__global__ void conv_wcat(const float* __restrict__ Wva, const float* __restrict__ Wvb,
                          const float* __restrict__ Wa, const float* __restrict__ Wb,
                          unsigned short* __restrict__ o) {
  const int n = N_U * D_HM;
  for (int i = blockIdx.x*blockDim.x + threadIdx.x; i < n; i += gridDim.x*blockDim.x) {
    int r = i / D_HM, col = i - r * D_HM;
    float v;
    if (r < 96)       v = Wva[r*D_HM + col];
    else if (r < 192) v = Wvb[(r-96)*D_HM + col];
    else if (r < 194) v = Wa[(r-192)*D_HM + col];
    else if (r < 196) v = Wb[(r-194)*D_HM + col];
    else              v = 0.f;
    o[i] = f2bf(v);
  }
}

// ---------------------------------------------------------------- GEMM1: Y = [in|h|m] @ W_h^T  (pre-LN, f32)
// 128x128 tile, BK=32, 4 waves. A: reg-staged f32->bf16 from 3 sources (each
// 32-wide k-chunk lies in exactly one source; boundaries 512/1536 are /32).
// B: bf16 via global_load_lds. bn = blockIdx&7 -> bn==XCD (W panel L2-resident).
__global__ __launch_bounds__(256, 2) void gemm1(
    const float* __restrict__ Xin, const float* __restrict__ Hp,
    const float* __restrict__ Mp,
    const unsigned short* __restrict__ W,   // 1024 x 2688 bf16
    float* __restrict__ Y) {                // 16384 x 1024 f32
  __shared__ __align__(16) unsigned short As[128*32];
  __shared__ __align__(16) unsigned short Bs[128*32];
  const int tid  = threadIdx.x;
  const int lane = tid & 63;
  const int wave = tid >> 6;
  const int bn = blockIdx.x & 7;        // XCD-aligned column panel
  const int bm = blockIdx.x >> 3;
  const int wr = wave >> 1, wc = wave & 1;
  const int lr = lane & 15, kh = lane >> 4;

  f32x4 acc[4][4];
  #pragma unroll
  for (int i = 0; i < 4; ++i)
    #pragma unroll
    for (int j = 0; j < 4; ++j) acc[i][j] = (f32x4)(0.f);

  const unsigned short* Wbase = W + (size_t)(bn*128) * D_C;
  const int s0 = tid, s1 = tid + 256;
  // A reg-stage: 2 threads/row, 16 f32 each
  const int ar    = tid >> 1;
  const int acoff = (tid & 1) * 16;

  for (int k0 = 0; k0 < D_C; k0 += 32) {
    const float* src; int ld, kk;
    if (k0 < 512)       { src = Xin; ld = D_IN;  kk = k0; }
    else if (k0 < 1536) { src = Hp;  ld = D_HID; kk = k0 - 512; }
    else                { src = Mp;  ld = D_MEM; kk = k0 - 1536; }
    const float4* arow = (const float4*)(src + (size_t)(bm*128 + ar)*ld + kk + acoff);
    float4 v0 = arow[0], v1 = arow[1], v2 = arow[2], v3 = arow[3];

    GLOAD16(Wbase + (size_t)(s0>>2)*D_C + k0 + (s0&3)*8, Bs + s0*8);
    GLOAD16(Wbase + (size_t)(s1>>2)*D_C + k0 + (s1&3)*8, Bs + s1*8);

    bf16x8 p0, p1;
    p0[0]=f2bf(v0.x); p0[1]=f2bf(v0.y); p0[2]=f2bf(v0.z); p0[3]=f2bf(v0.w);
    p0[4]=f2bf(v1.x); p0[5]=f2bf(v1.y); p0[6]=f2bf(v1.z); p0[7]=f2bf(v1.w);
    p1[0]=f2bf(v2.x); p1[1]=f2bf(v2.y); p1[2]=f2bf(v2.z); p1[3]=f2bf(v2.w);
    p1[4]=f2bf(v3.x); p1[5]=f2bf(v3.y); p1[6]=f2bf(v3.z); p1[7]=f2bf(v3.w);
    *(bf16x8*)(As + ar*32 + acoff)     = p0;
    *(bf16x8*)(As + ar*32 + acoff + 8) = p1;

    __syncthreads();   // drains vmcnt (B) + lgkmcnt (A writes)
    bf16x8 a[4], b[4];
    #pragma unroll
    for (int mi = 0; mi < 4; ++mi)
      a[mi] = *(const bf16x8*)(As + (wr*64 + mi*16 + lr)*32 + kh*8);
    #pragma unroll
    for (int ni = 0; ni < 4; ++ni)
      b[ni] = *(const bf16x8*)(Bs + (wc*64 + ni*16 + lr)*32 + kh*8);
    #pragma unroll
    for (int mi = 0; mi < 4; ++mi)
      #pragma unroll
      for (int ni = 0; ni < 4; ++ni)
        acc[mi][ni] = __builtin_amdgcn_mfma_f32_16x16x32_bf16(a[mi], b[ni], acc[mi][ni], 0, 0, 0);
    __syncthreads();
  }
  const int orow0 = bm*128 + wr*64;
  const int ocol0 = bn*128 + wc*64;
  #pragma unroll
  for (int mi = 0; mi < 4; ++mi)
    #pragma unroll
    for (int ni = 0; ni < 4; ++ni)
      #pragma unroll
      for (int i = 0; i < 4; ++i) {
        int r  = orow0 + mi*16 + kh*4 + i;     // C row = (lane>>4)*4 + reg
        int cc = ocol0 + ni*16 + lr;           // C col = lane&15
        Y[(size_t)r * D_HID + cc] = acc[mi][ni][i];
      }
}

// ---------------------------------------------------------------- LN + ReLU, emit f32 h (d_out) + bf16 h (hmh)
__global__ __launch_bounds__(256) void ln_relu(
    float* __restrict__ Y, const float* __restrict__ bh,
    const float* __restrict__ g, const float* __restrict__ bb,
    unsigned short* __restrict__ hmh) {       // 16384 x 1024 bf16
  const int row = blockIdx.x;
  const int t = threadIdx.x;
  float4 x = ((const float4*)(Y + (size_t)row * D_HID))[t];
  float4 b4 = ((const float4*)bh)[t];
  x.x += b4.x; x.y += b4.y; x.z += b4.z; x.w += b4.w;
  float s  = x.x + x.y + x.z + x.w;
  float sq = x.x*x.x + x.y*x.y + x.z*x.z + x.w*x.w;
  #pragma unroll
  for (int off = 32; off >= 1; off >>= 1) {
    s  += __shfl_down(s,  off, 64);
    sq += __shfl_down(sq, off, 64);
  }
  __shared__ float red[8];
  if ((t & 63) == 0) { red[t >> 6] = s; red[4 + (t >> 6)] = sq; }
  __syncthreads();
  float ts = red[0]+red[1]+red[2]+red[3];
  float tq = red[4]+red[5]+red[6]+red[7];
  float mu = ts * (1.f/1024.f);
  float var = tq * (1.f/1024.f) - mu*mu;
  float rstd = rsqrtf(var + 1e-5f);
  float4 g4  = ((const float4*)g)[t];
  float4 bb4 = ((const float4*)bb)[t];
  float4 o;
  o.x = fmaxf(0.f, (x.x - mu)*rstd*g4.x + bb4.x);
  o.y = fmaxf(0.f, (x.y - mu)*rstd*g4.y + bb4.y);
  o.z = fmaxf(0.f, (x.z - mu)*rstd*g4.z + bb4.z);
  o.w = fmaxf(0.f, (x.w - mu)*rstd*g4.w + bb4.w);
  ((float4*)(Y + (size_t)row * D_HID))[t] = o;
  ushort4 ob; ob.x=f2bf(o.x); ob.y=f2bf(o.y); ob.z=f2bf(o.z); ob.w=f2bf(o.w);
  *(ushort4*)(hmh + (size_t)row * D_HID + t*4) = ob;
}

// ---------------------------------------------------------------- GEMM2: U = [h|m] @ Wcat^T  (16384 x 224)
// 64x224 tile, BK=32, 8 waves. A: k<1024 from hmh (bf16, global_load_lds);
// k>=1024 reg-staged f32->bf16 from m_prev.
__global__ __launch_bounds__(512, 2) void gemm2(
    const unsigned short* __restrict__ Hb,  // 16384 x 1024 bf16
    const float* __restrict__ Mp,           // 16384 x 1152 f32
    const unsigned short* __restrict__ W,   // 224 x 2176 bf16
    float* __restrict__ U) {                // 16384 x 224 f32
  __shared__ __align__(16) unsigned short As[64*32];
  __shared__ __align__(16) unsigned short Bs[224*32];
  const int tid  = threadIdx.x;
  const int lane = tid & 63;
  const int wave = tid >> 6;
  const int wr = wave >> 1, wc = wave & 1;
  const int lr = lane & 15, kh = lane >> 4;
  const int bm = blockIdx.x;

  f32x4 acc[7];
  #pragma unroll
  for (int i = 0; i < 7; ++i) acc[i] = (f32x4)(0.f);

  for (int k0 = 0; k0 < D_HM; k0 += 32) {
    // ---- A tile
    if (k0 < 1024) {
      if (tid < 256)
        GLOAD16(Hb + (size_t)(bm*64 + (tid>>2))*D_HID + k0 + (tid&3)*8, As + tid*8);
    } else {
      if (tid < 128) {
        const int ar = tid >> 1, acoff = (tid & 1) * 16;
        const float4* arow = (const float4*)(Mp + (size_t)(bm*64 + ar)*D_MEM + (k0-1024) + acoff);
        float4 v0 = arow[0], v1 = arow[1], v2 = arow[2], v3 = arow[3];
        bf16x8 p0, p1;
        p0[0]=f2bf(v0.x); p0[1]=f2bf(v0.y); p0[2]=f2bf(v0.z); p0[3]=f2bf(v0.w);
        p0[4]=f2bf(v1.x); p0[5]=f2bf(v1.y); p0[6]=f2bf(v1.z); p0[7]=f2bf(v1.w);
        p1[0]=f2bf(v2.x); p1[1]=f2bf(v2.y); p1[2]=f2bf(v2.z); p1[3]=f2bf(v2.w);
        p1[4]=f2bf(v3.x); p1[5]=f2bf(v3.y); p1[6]=f2bf(v3.z); p1[7]=f2bf(v3.w);
        *(bf16x8*)(As + ar*32 + acoff)     = p0;
        *(bf16x8*)(As + ar*32 + acoff + 8) = p1;
      }
    }
    // ---- B tile: 896 slots of 16B
    if (tid >= 256) {
      int sb = tid - 256;
      GLOAD16(W + (size_t)(sb>>2)*D_HM + k0 + (sb&3)*8, Bs + sb*8);
    }
    {
      int sb = tid + 256;
      GLOAD16(W + (size_t)(sb>>2)*D_HM + k0 + (sb&3)*8, Bs + sb*8);
    }
    if (tid < 128) {
      int sb = tid + 768;
      GLOAD16(W + (size_t)(sb>>2)*D_HM + k0 + (sb&3)*8, Bs + sb*8);
    }
    __syncthreads();
    bf16x8 a = *(const bf16x8*)(As + (wr*16 + lr)*32 + kh*8);
    #pragma unroll
    for (int ni = 0; ni < 7; ++ni) {
      bf16x8 b = *(const bf16x8*)(Bs + (wc*112 + ni*16 + lr)*32 + kh*8);
      acc[ni] = __builtin_amdgcn_mfma_f32_16x16x32_bf16(a, b, acc[ni], 0, 0, 0);
    }
    __syncthreads();
  }
  const int orow = bm*64 + wr*16 + kh*4;
  #pragma unroll
  for (int ni = 0; ni < 7; ++ni) {
    int cc = wc*112 + ni*16 + lr;
    #pragma unroll
    for (int i = 0; i < 4; ++i)
      U[(size_t)(orow + i) * N_U + cc] = acc[ni][i];
  }
}

// ---------------------------------------------------------------- gate: m = m_prev + add - forget
// Factorized 5-norm: ||v_k||_5^5 = (sum_r |u1_r|^5)(sum_c |u2_c|^5)
__global__ __launch_bounds__(256) void gate(
    const float* __restrict__ U,
    const float* __restrict__ ba, const float* __restrict__ bbt,
    const float* __restrict__ bva, const float* __restrict__ bvb,
    const float* __restrict__ mp, float* __restrict__ Mo) {
  const int row = blockIdx.x;
  const int t = threadIdx.x;
  __shared__ float su[196];
  __shared__ float p5[192];
  __shared__ float S[6];
  __shared__ float coef[4];
  __shared__ float qa[24], qb[24];
  const float* urow = U + (size_t)row * N_U;
  if (t < 196) {
    float bias;
    if (t < 96)       bias = bva[t];
    else if (t < 192) bias = bvb[t - 96];
    else if (t < 194) bias = ba[t - 192];
    else              bias = bbt[t - 194];
    float v = urow[t] + bias;
    su[t] = v;
    if (t < 192) { float a = fabsf(v); p5[t] = a*a*a*a*a; }
  }
  __syncthreads();
  if (t < 6) {
    const int start[6] = {0, 24, 48, 96, 120, 144};
    const int cnt[6]   = {24, 24, 48, 24, 24, 48};
    float ssum = 0.f;
    for (int i = 0; i < cnt[t]; ++i) ssum += p5[start[t] + i];
    S[t] = ssum;
  }
  __syncthreads();
  if (t < 2) {
    float S2  = (t == 0) ? S[2] : S[5];
    float a0  = (t == 0) ? su[192] : su[194];
    float a1  = (t == 0) ? su[193] : su[195];
    float S10 = (t == 0) ? S[0] : S[3];
    float S11 = (t == 0) ? S[1] : S[4];
    float n0 = powf(S10 * S2, 0.2f);
    float n1 = powf(S11 * S2, 0.2f);
    coef[t*2 + 0] = 0.5f * a0 / fmaxf(n0, 1e-12f);
    coef[t*2 + 1] = 0.5f * a1 / fmaxf(n1, 1e-12f);
  }
  __syncthreads();
  if (t < 24)       qa[t]     = coef[0]*su[t]       + coef[1]*su[24 + t];
  else if (t < 48)  qb[t-24]  = coef[2]*su[96+t-24] + coef[3]*su[120 + t - 24];
  __syncthreads();
  const float4* mp4 = (const float4*)(mp + (size_t)row * D_MEM);
  float4*       mo4 = (float4*)(Mo + (size_t)row * D_MEM);
  for (int p4 = t; p4 < 288; p4 += 256) {
    float4 m = mp4[p4];
    int p = p4 * 4;
    int r = p / 48, c = p % 48;        // c multiple of 4, never wraps within float4
    float A0 = qa[r], B0 = qb[r];
    float4 o;
    o.x = m.x + su[48 + c    ]*A0 - su[144 + c    ]*B0;
    o.y = m.y + su[48 + c + 1]*A0 - su[144 + c + 1]*B0;
    o.z = m.z + su[48 + c + 2]*A0 - su[144 + c + 2]*B0;
    o.w = m.w + su[48 + c + 3]*A0 - su[144 + c + 3]*B0;
    mo4[p4] = o;
  }
}

// ---------------------------------------------------------------- launch
extern "C" void kernel_launch(void* const* d_in, const int* in_sizes, int n_in,
                              void* d_out, int out_size, void* d_ws, size_t ws_size,
                              hipStream_t stream) {
  const float* input  = (const float*)d_in[0];
  const float* h_prev = (const float*)d_in[1];
  const float* m_prev = (const float*)d_in[2];
  const float* W_h    = (const float*)d_in[3];
  const float* b_h    = (const float*)d_in[4];
  const float* ln_g   = (const float*)d_in[5];
  const float* ln_b   = (const float*)d_in[6];
  const float* b_a    = (const float*)d_in[8];
  const float* W_b    = (const float*)d_in[9];
  const float* b_b    = (const float*)d_in[10];
  const float* W_a    = (const float*)d_in[7];
  const float* W_va   = (const float*)d_in[11];
  const float* b_va   = (const float*)d_in[12];
  const float* W_vb   = (const float*)d_in[13];
  const float* b_vb   = (const float*)d_in[14];

  const size_t off_wh   = 0;
  const size_t off_wcat = off_wh   + (size_t)D_HID * D_C * 2;       //  5,505,024
  const size_t off_hmh  = off_wcat + (size_t)N_U * D_HM * 2;        //  6,479,872
  const size_t off_U    = off_hmh  + (size_t)B_ROWS * D_HID * 2;    // 40,034,304
  const size_t need     = off_U    + (size_t)B_ROWS * N_U * 4;      // 54,714,368
  if (ws_size < need) return;

  char* ws = (char*)d_ws;
  unsigned short* wh_bf = (unsigned short*)(ws + off_wh);
  unsigned short* wc_bf = (unsigned short*)(ws + off_wcat);
  unsigned short* hmh   = (unsigned short*)(ws + off_hmh);
  float*          Ubuf  = (float*)(ws + off_U);

  float* h_out = (float*)d_out;                     // B x 1024
  float* m_out = h_out + (size_t)B_ROWS * D_HID;    // B x 1152

  conv_w4  <<<1024, 256, 0, stream>>>(W_h, wh_bf, (D_HID * D_C) / 4);
  conv_wcat<<<1024, 256, 0, stream>>>(W_va, W_vb, W_a, W_b, wc_bf);
  gemm1    <<<1024, 256, 0, stream>>>(input, h_prev, m_prev, wh_bf, h_out);
  ln_relu  <<<B_ROWS, 256, 0, stream>>>(h_out, b_h, ln_g, ln_b, hmh);
  gemm2    <<<B_ROWS / 64, 512, 0, stream>>>(hmh, m_prev, wc_bf, Ubuf);
  gate     <<<B_ROWS, 256, 0, stream>>>(Ubuf, b_a, b_b, b_va, b_vb, m_prev, m_out);
}

// Round 5
// 504.691 us; speedup vs baseline: 1.1593x; 1.1593x over previous
//
#include <hip/hip_runtime.h>
#include <hip/hip_bf16.h>
#include <cstdint>
#include <cstddef>

#define B_ROWS 16384
#define D_IN   512
#define D_HID  1024
#define D_MEM  1152
#define D_C    2688   // 512+1024+1152
#define D_HM   2176   // 1024+1152
#define N_U    224    // padded from 196

typedef __attribute__((ext_vector_type(8))) short bf16x8;
typedef __attribute__((ext_vector_type(4))) float f32x4;

static __device__ __forceinline__ unsigned short f2bf(float f) {
  unsigned u = __float_as_uint(f);
  unsigned r = u + 0x7fffu + ((u >> 16) & 1u);   // RNE
  return (unsigned short)(r >> 16);
}

#define GLOAD16(g, l) __builtin_amdgcn_global_load_lds( \
    (const __attribute__((address_space(1))) void*)(g), \
    (__attribute__((address_space(3))) void*)(l), 16, 0, 0)

// ---------------------------------------------------------------- convert inputs -> bf16 (separate buffers, no concat)
__global__ __launch_bounds__(256) void convert3(
    const float* __restrict__ x, const float* __restrict__ h, const float* __restrict__ m,
    unsigned short* __restrict__ xb, unsigned short* __restrict__ hb, unsigned short* __restrict__ mb) {
  const int stride = gridDim.x * blockDim.x;
  const int t0 = blockIdx.x * blockDim.x + threadIdx.x;
  const int nx = B_ROWS * D_IN / 4, nh = B_ROWS * D_HID / 4, nm = B_ROWS * D_MEM / 4;
  for (int i = t0; i < nx; i += stride) {
    float4 v = ((const float4*)x)[i];
    ushort4 o; o.x=f2bf(v.x); o.y=f2bf(v.y); o.z=f2bf(v.z); o.w=f2bf(v.w);
    ((ushort4*)xb)[i] = o;
  }
  for (int i = t0; i < nh; i += stride) {
    float4 v = ((const float4*)h)[i];
    ushort4 o; o.x=f2bf(v.x); o.y=f2bf(v.y); o.z=f2bf(v.z); o.w=f2bf(v.w);
    ((ushort4*)hb)[i] = o;
  }
  for (int i = t0; i < nm; i += stride) {
    float4 v = ((const float4*)m)[i];
    ushort4 o; o.x=f2bf(v.x); o.y=f2bf(v.y); o.z=f2bf(v.z); o.w=f2bf(v.w);
    ((ushort4*)mb)[i] = o;
  }
}

// ---------------------------------------------------------------- weight conversions
__global__ void conv_w4(const float* __restrict__ W, unsigned short* __restrict__ o, int n4) {
  for (int i = blockIdx.x*blockDim.x + threadIdx.x; i < n4; i += gridDim.x*blockDim.x) {
    float4 v = ((const float4*)W)[i];
    ushort4 u; u.x=f2bf(v.x); u.y=f2bf(v.y); u.z=f2bf(v.z); u.w=f2bf(v.w);
    ((ushort4*)o)[i] = u;
  }
}

// Wcat rows: [0:96)=W_va, [96:192)=W_vb, [192:194)=W_a, [194:196)=W_b, [196:224)=0
__global__ void conv_wcat(const float* __restrict__ Wva, const float* __restrict__ Wvb,
                          const float* __restrict__ Wa, const float* __restrict__ Wb,
                          unsigned short* __restrict__ o) {
  const int n = N_U * D_HM;
  for (int i = blockIdx.x*blockDim.x + threadIdx.x; i < n; i += gridDim.x*blockDim.x) {
    int r = i / D_HM, col = i - r * D_HM;
    float v;
    if (r < 96)       v = Wva[r*D_HM + col];
    else if (r < 192) v = Wvb[(r-96)*D_HM + col];
    else if (r < 194) v = Wa[(r-192)*D_HM + col];
    else if (r < 196) v = Wb[(r-194)*D_HM + col];
    else              v = 0.f;
    o[i] = f2bf(v);
  }
}

// ---------------------------------------------------------------- GEMM1: Y = [in|h|m] @ W_h^T  (pre-LN, f32)
// 128x128 tile, BK=32, 4 waves, all-LDS-direct (bf16 sources). Each BK chunk
// lies in exactly one source (boundaries 512/1536 are /32). Mapping bm=blk&127:
// same-bm blocks are 128 apart -> same XCD -> A panel fetched once per L2.
__global__ __launch_bounds__(256, 2) void gemm1(
    const unsigned short* __restrict__ Xb,  // 16384 x 512
    const unsigned short* __restrict__ Hb,  // 16384 x 1024
    const unsigned short* __restrict__ Mb,  // 16384 x 1152
    const unsigned short* __restrict__ W,   // 1024 x 2688 bf16
    float* __restrict__ Y) {                // 16384 x 1024 f32
  __shared__ __align__(16) unsigned short As[128*32];
  __shared__ __align__(16) unsigned short Bs[128*32];
  const int tid  = threadIdx.x;
  const int lane = tid & 63;
  const int wave = tid >> 6;
  const int bm = blockIdx.x & 127;
  const int bn = blockIdx.x >> 7;
  const int wr = wave >> 1, wc = wave & 1;
  const int lr = lane & 15, kh = lane >> 4;

  f32x4 acc[4][4];
  #pragma unroll
  for (int i = 0; i < 4; ++i)
    #pragma unroll
    for (int j = 0; j < 4; ++j) acc[i][j] = (f32x4)(0.f);

  const unsigned short* Wbase = W + (size_t)(bn*128) * D_C;
  const int s0 = tid, s1 = tid + 256;
  const int ar0 = s0 >> 2, ac0 = (s0 & 3) * 8;
  const int ar1 = s1 >> 2, ac1 = (s1 & 3) * 8;

  for (int k0 = 0; k0 < D_C; k0 += 32) {
    const unsigned short* asrc; int ald, akk;
    if (k0 < 512)       { asrc = Xb; ald = D_IN;  akk = k0; }
    else if (k0 < 1536) { asrc = Hb; ald = D_HID; akk = k0 - 512; }
    else                { asrc = Mb; ald = D_MEM; akk = k0 - 1536; }
    GLOAD16(asrc + (size_t)(bm*128 + ar0)*ald + akk + ac0, As + s0*8);
    GLOAD16(asrc + (size_t)(bm*128 + ar1)*ald + akk + ac1, As + s1*8);
    GLOAD16(Wbase + (size_t)ar0*D_C + k0 + ac0, Bs + s0*8);
    GLOAD16(Wbase + (size_t)ar1*D_C + k0 + ac1, Bs + s1*8);
    __syncthreads();
    bf16x8 a[4], b[4];
    #pragma unroll
    for (int mi = 0; mi < 4; ++mi)
      a[mi] = *(const bf16x8*)(As + (wr*64 + mi*16 + lr)*32 + kh*8);
    #pragma unroll
    for (int ni = 0; ni < 4; ++ni)
      b[ni] = *(const bf16x8*)(Bs + (wc*64 + ni*16 + lr)*32 + kh*8);
    #pragma unroll
    for (int mi = 0; mi < 4; ++mi)
      #pragma unroll
      for (int ni = 0; ni < 4; ++ni)
        acc[mi][ni] = __builtin_amdgcn_mfma_f32_16x16x32_bf16(a[mi], b[ni], acc[mi][ni], 0, 0, 0);
    __syncthreads();
  }
  const int orow0 = bm*128 + wr*64;
  const int ocol0 = bn*128 + wc*64;
  #pragma unroll
  for (int mi = 0; mi < 4; ++mi)
    #pragma unroll
    for (int ni = 0; ni < 4; ++ni)
      #pragma unroll
      for (int i = 0; i < 4; ++i) {
        int r  = orow0 + mi*16 + kh*4 + i;     // C row = (lane>>4)*4 + reg
        int cc = ocol0 + ni*16 + lr;           // C col = lane&15
        Y[(size_t)r * D_HID + cc] = acc[mi][ni][i];
      }
}

// ---------------------------------------------------------------- LN + ReLU, emit f32 h (d_out) + bf16 h (hmh)
__global__ __launch_bounds__(256) void ln_relu(
    float* __restrict__ Y, const float* __restrict__ bh,
    const float* __restrict__ g, const float* __restrict__ bb,
    unsigned short* __restrict__ hmh) {       // 16384 x 1024 bf16
  const int row = blockIdx.x;
  const int t = threadIdx.x;
  float4 x = ((const float4*)(Y + (size_t)row * D_HID))[t];
  float4 b4 = ((const float4*)bh)[t];
  x.x += b4.x; x.y += b4.y; x.z += b4.z; x.w += b4.w;
  float s  = x.x + x.y + x.z + x.w;
  float sq = x.x*x.x + x.y*x.y + x.z*x.z + x.w*x.w;
  #pragma unroll
  for (int off = 32; off >= 1; off >>= 1) {
    s  += __shfl_down(s,  off, 64);
    sq += __shfl_down(sq, off, 64);
  }
  __shared__ float red[8];
  if ((t & 63) == 0) { red[t >> 6] = s; red[4 + (t >> 6)] = sq; }
  __syncthreads();
  float ts = red[0]+red[1]+red[2]+red[3];
  float tq = red[4]+red[5]+red[6]+red[7];
  float mu = ts * (1.f/1024.f);
  float var = tq * (1.f/1024.f) - mu*mu;
  float rstd = rsqrtf(var + 1e-5f);
  float4 g4  = ((const float4*)g)[t];
  float4 bb4 = ((const float4*)bb)[t];
  float4 o;
  o.x = fmaxf(0.f, (x.x - mu)*rstd*g4.x + bb4.x);
  o.y = fmaxf(0.f, (x.y - mu)*rstd*g4.y + bb4.y);
  o.z = fmaxf(0.f, (x.z - mu)*rstd*g4.z + bb4.z);
  o.w = fmaxf(0.f, (x.w - mu)*rstd*g4.w + bb4.w);
  ((float4*)(Y + (size_t)row * D_HID))[t] = o;
  ushort4 ob; ob.x=f2bf(o.x); ob.y=f2bf(o.y); ob.z=f2bf(o.z); ob.w=f2bf(o.w);
  *(ushort4*)(hmh + (size_t)row * D_HID + t*4) = ob;
}

// ---------------------------------------------------------------- GEMM2+gate fused
// 64x224 tile (full U width per block), BK=32, 8 waves. Epilogue runs the
// factorized-5-norm gate from LDS: m = m_prev + u2a*qa - u2b*qb.
// LDS: [bias 224 f32][union {As 4K + Bs 14K} | {U 57344, sm 2048, coef 1024, q 12288}]
__global__ __launch_bounds__(512, 1) void gemm2g(
    const unsigned short* __restrict__ Hb,  // 16384 x 1024 bf16 (post-LN h)
    const unsigned short* __restrict__ Mb,  // 16384 x 1152 bf16 (m_prev)
    const unsigned short* __restrict__ W,   // 224 x 2176 bf16
    const float* __restrict__ ba, const float* __restrict__ bbt,
    const float* __restrict__ bva, const float* __restrict__ bvb,
    const float* __restrict__ mp,           // f32 m_prev
    float* __restrict__ Mo) {               // f32 m out
  __shared__ __align__(16) char smem[896 + 57344 + 2048 + 1024 + 12288];
  float*          bias_s = (float*)smem;                       // 224
  unsigned short* As     = (unsigned short*)(smem + 896);      // 64*32
  unsigned short* Bs     = (unsigned short*)(smem + 896 + 4096); // 224*32
  float*          Us     = (float*)(smem + 896);               // 64*224
  float*          sm_s   = (float*)(smem + 896 + 57344);       // 64*8
  float*          coef_s = (float*)(smem + 896 + 57344 + 2048);// 64*4
  float*          q_s    = (float*)(smem + 896 + 57344 + 3072);// 64*48

  const int tid  = threadIdx.x;
  const int lane = tid & 63;
  const int wave = tid >> 6;
  const int wr = wave >> 1, wc = wave & 1;
  const int lr = lane & 15, kh = lane >> 4;
  const int bm = blockIdx.x;

  if (tid < N_U) {
    int c = tid; float v;
    if (c < 96)       v = bva[c];
    else if (c < 192) v = bvb[c - 96];
    else if (c < 194) v = ba[c - 192];
    else if (c < 196) v = bbt[c - 194];
    else              v = 0.f;
    bias_s[c] = v;
  }

  f32x4 acc[7];
  #pragma unroll
  for (int i = 0; i < 7; ++i) acc[i] = (f32x4)(0.f);

  for (int k0 = 0; k0 < D_HM; k0 += 32) {
    // ---- A tile (64 rows x 32)
    if (tid < 256) {
      const unsigned short* asrc; int ald, akk;
      if (k0 < 1024) { asrc = Hb; ald = D_HID; akk = k0; }
      else           { asrc = Mb; ald = D_MEM; akk = k0 - 1024; }
      GLOAD16(asrc + (size_t)(bm*64 + (tid>>2))*ald + akk + (tid&3)*8, As + tid*8);
    }
    // ---- B tile: 896 slots of 16B
    if (tid >= 256) {
      int sb = tid - 256;
      GLOAD16(W + (size_t)(sb>>2)*D_HM + k0 + (sb&3)*8, Bs + sb*8);
    }
    {
      int sb = tid + 256;
      GLOAD16(W + (size_t)(sb>>2)*D_HM + k0 + (sb&3)*8, Bs + sb*8);
    }
    if (tid < 128) {
      int sb = tid + 768;
      GLOAD16(W + (size_t)(sb>>2)*D_HM + k0 + (sb&3)*8, Bs + sb*8);
    }
    __syncthreads();
    bf16x8 a = *(const bf16x8*)(As + (wr*16 + lr)*32 + kh*8);
    #pragma unroll
    for (int ni = 0; ni < 7; ++ni) {
      bf16x8 b = *(const bf16x8*)(Bs + (wc*112 + ni*16 + lr)*32 + kh*8);
      acc[ni] = __builtin_amdgcn_mfma_f32_16x16x32_bf16(a, b, acc[ni], 0, 0, 0);
    }
    __syncthreads();
  }

  // ---- (a) acc -> Us with bias (staging LDS now dead)
  {
    const int row = wr*16 + kh*4;
    #pragma unroll
    for (int ni = 0; ni < 7; ++ni) {
      int cc = wc*112 + ni*16 + lr;
      float bb4 = bias_s[cc];
      #pragma unroll
      for (int i = 0; i < 4; ++i)
        Us[(row + i)*N_U + cc] = acc[ni][i] + bb4;
    }
  }
  __syncthreads();

  const int gr = tid >> 3;     // row 0..63
  const int gj = tid & 7;      // 8 threads per row
  // ---- (b) segment partial sums of |su|^5: thread gj covers [gj*24, gj*24+24)
  {
    const float* su = Us + gr*N_U;
    float ssum = 0.f;
    #pragma unroll 4
    for (int i = 0; i < 24; ++i) {
      float a = fabsf(su[gj*24 + i]);
      float a2 = a*a;
      ssum += a2*a2*a;
    }
    sm_s[gr*8 + gj] = ssum;
  }
  __syncthreads();
  // ---- (c) coefs (one thread per row)
  if (gj == 0) {
    const float* sm = sm_s + gr*8;
    const float* su = Us + gr*N_U;
    float S2a = sm[2] + sm[3];       // sum |u2a|^5
    float S2b = sm[6] + sm[7];       // sum |u2b|^5
    float n0 = powf(sm[0]*S2a, 0.2f);
    float n1 = powf(sm[1]*S2a, 0.2f);
    float n2 = powf(sm[4]*S2b, 0.2f);
    float n3 = powf(sm[5]*S2b, 0.2f);
    coef_s[gr*4+0] = 0.5f * su[192] / fmaxf(n0, 1e-12f);
    coef_s[gr*4+1] = 0.5f * su[193] / fmaxf(n1, 1e-12f);
    coef_s[gr*4+2] = 0.5f * su[194] / fmaxf(n2, 1e-12f);
    coef_s[gr*4+3] = 0.5f * su[195] / fmaxf(n3, 1e-12f);
  }
  __syncthreads();
  // ---- (d) q vectors: 48 per row, 6 per thread
  {
    const float* su = Us + gr*N_U;
    const float* cf = coef_s + gr*4;
    #pragma unroll
    for (int i = 0; i < 6; ++i) {
      int mq = gj*6 + i;
      float v;
      if (mq < 24) v = cf[0]*su[mq]        + cf[1]*su[24 + mq];
      else         v = cf[2]*su[96 + mq-24] + cf[3]*su[120 + mq-24];
      q_s[gr*48 + mq] = v;
    }
  }
  __syncthreads();
  // ---- (e) m = m_prev + u2a*qa - u2b*qb   (64 rows x 1152)
  {
    const float4* mp4 = (const float4*)(mp + (size_t)(bm*64) * D_MEM);
    float4*       mo4 = (float4*)(Mo + (size_t)(bm*64) * D_MEM);
    for (int idx = tid; idx < 64*288; idx += 512) {
      int row = idx / 288;
      int p4  = idx - row*288;
      int p = p4*4;
      int rr = p/48, c = p - rr*48;    // c multiple of 4
      const float* su = Us + row*N_U;
      float A0 = q_s[row*48 + rr], B0 = q_s[row*48 + 24 + rr];
      float4 m = mp4[row*288 + p4];
      float4 o;
      o.x = m.x + su[48 + c    ]*A0 - su[144 + c    ]*B0;
      o.y = m.y + su[48 + c + 1]*A0 - su[144 + c + 1]*B0;
      o.z = m.z + su[48 + c + 2]*A0 - su[144 + c + 2]*B0;
      o.w = m.w + su[48 + c + 3]*A0 - su[144 + c + 3]*B0;
      mo4[row*288 + p4] = o;
    }
  }
}

// ---------------------------------------------------------------- launch
extern "C" void kernel_launch(void* const* d_in, const int* in_sizes, int n_in,
                              void* d_out, int out_size, void* d_ws, size_t ws_size,
                              hipStream_t stream) {
  const float* input  = (const float*)d_in[0];
  const float* h_prev = (const float*)d_in[1];
  const float* m_prev = (const float*)d_in[2];
  const float* W_h    = (const float*)d_in[3];
  const float* b_h    = (const float*)d_in[4];
  const float* ln_g   = (const float*)d_in[5];
  const float* ln_b   = (const float*)d_in[6];
  const float* W_a    = (const float*)d_in[7];
  const float* b_a    = (const float*)d_in[8];
  const float* W_b    = (const float*)d_in[9];
  const float* b_b    = (const float*)d_in[10];
  const float* W_va   = (const float*)d_in[11];
  const float* b_va   = (const float*)d_in[12];
  const float* W_vb   = (const float*)d_in[13];
  const float* b_vb   = (const float*)d_in[14];

  const size_t off_wh   = 0;                                        //  5,505,024
  const size_t off_wcat = off_wh   + (size_t)D_HID * D_C * 2;
  const size_t off_xb   = off_wcat + (size_t)N_U * D_HM * 2;        //  6,479,872
  const size_t off_hb   = off_xb   + (size_t)B_ROWS * D_IN * 2;     // 23,257,088
  const size_t off_mb   = off_hb   + (size_t)B_ROWS * D_HID * 2;    // 56,811,520
  const size_t off_hmh  = off_mb   + (size_t)B_ROWS * D_MEM * 2;    // 94,560,256
  const size_t need     = off_hmh  + (size_t)B_ROWS * D_HID * 2;    // 128,114,688
  if (ws_size < need) return;

  char* ws = (char*)d_ws;
  unsigned short* wh_bf = (unsigned short*)(ws + off_wh);
  unsigned short* wc_bf = (unsigned short*)(ws + off_wcat);
  unsigned short* xb    = (unsigned short*)(ws + off_xb);
  unsigned short* hb    = (unsigned short*)(ws + off_hb);
  unsigned short* mb    = (unsigned short*)(ws + off_mb);
  unsigned short* hmh   = (unsigned short*)(ws + off_hmh);

  float* h_out = (float*)d_out;                     // B x 1024
  float* m_out = h_out + (size_t)B_ROWS * D_HID;    // B x 1152

  convert3 <<<2048, 256, 0, stream>>>(input, h_prev, m_prev, xb, hb, mb);
  conv_w4  <<<1024, 256, 0, stream>>>(W_h, wh_bf, (D_HID * D_C) / 4);
  conv_wcat<<<256, 256, 0, stream>>>(W_va, W_vb, W_a, W_b, wc_bf);
  gemm1    <<<1024, 256, 0, stream>>>(xb, hb, mb, wh_bf, h_out);
  ln_relu  <<<B_ROWS, 256, 0, stream>>>(h_out, b_h, ln_g, ln_b, hmh);
  gemm2g   <<<B_ROWS / 64, 512, 0, stream>>>(hmh, mb, wc_bf, b_a, b_b, b_va, b_vb, m_prev, m_out);
}

// Round 6
// 484.587 us; speedup vs baseline: 1.2074x; 1.0415x over previous
//
#include <hip/hip_runtime.h>
#include <hip/hip_bf16.h>
#include <cstdint>
#include <cstddef>

#define B_ROWS 16384
#define D_IN   512
#define D_HID  1024
#define D_MEM  1152
#define D_C    2688   // 512+1024+1152
#define D_HM   2176   // 1024+1152
#define N_U    224    // padded from 196

typedef __attribute__((ext_vector_type(8))) short bf16x8;
typedef __attribute__((ext_vector_type(4))) float f32x4;

static __device__ __forceinline__ unsigned short f2bf(float f) {
  unsigned u = __float_as_uint(f);
  unsigned r = u + 0x7fffu + ((u >> 16) & 1u);   // RNE
  return (unsigned short)(r >> 16);
}

#define GLOAD16(g, l) __builtin_amdgcn_global_load_lds( \
    (const __attribute__((address_space(1))) void*)(g), \
    (__attribute__((address_space(3))) void*)(l), 16, 0, 0)

// ---------------------------------------------------------------- prep: all f32->bf16 conversions in ONE kernel
__global__ __launch_bounds__(256) void prep(
    const float* __restrict__ x, const float* __restrict__ h, const float* __restrict__ m,
    const float* __restrict__ Wh,
    const float* __restrict__ Wva, const float* __restrict__ Wvb,
    const float* __restrict__ Wa, const float* __restrict__ Wb,
    unsigned short* __restrict__ xb, unsigned short* __restrict__ hb,
    unsigned short* __restrict__ mb, unsigned short* __restrict__ whb,
    unsigned short* __restrict__ wcb) {
  const int stride = gridDim.x * blockDim.x;
  const int t0 = blockIdx.x * blockDim.x + threadIdx.x;
  const int nx = B_ROWS * D_IN / 4, nh = B_ROWS * D_HID / 4, nm = B_ROWS * D_MEM / 4;
  const int nw = D_HID * D_C / 4;
  for (int i = t0; i < nx; i += stride) {
    float4 v = ((const float4*)x)[i];
    ushort4 o; o.x=f2bf(v.x); o.y=f2bf(v.y); o.z=f2bf(v.z); o.w=f2bf(v.w);
    ((ushort4*)xb)[i] = o;
  }
  for (int i = t0; i < nh; i += stride) {
    float4 v = ((const float4*)h)[i];
    ushort4 o; o.x=f2bf(v.x); o.y=f2bf(v.y); o.z=f2bf(v.z); o.w=f2bf(v.w);
    ((ushort4*)hb)[i] = o;
  }
  for (int i = t0; i < nm; i += stride) {
    float4 v = ((const float4*)m)[i];
    ushort4 o; o.x=f2bf(v.x); o.y=f2bf(v.y); o.z=f2bf(v.z); o.w=f2bf(v.w);
    ((ushort4*)mb)[i] = o;
  }
  for (int i = t0; i < nw; i += stride) {
    float4 v = ((const float4*)Wh)[i];
    ushort4 o; o.x=f2bf(v.x); o.y=f2bf(v.y); o.z=f2bf(v.z); o.w=f2bf(v.w);
    ((ushort4*)whb)[i] = o;
  }
  // Wcat rows: [0:96)=W_va, [96:192)=W_vb, [192:194)=W_a, [194:196)=W_b, [196:224)=0
  const int nc = N_U * D_HM;
  for (int i = t0; i < nc; i += stride) {
    int r = i / D_HM, col = i - r * D_HM;
    float v;
    if (r < 96)       v = Wva[r*D_HM + col];
    else if (r < 192) v = Wvb[(r-96)*D_HM + col];
    else if (r < 194) v = Wa[(r-192)*D_HM + col];
    else if (r < 196) v = Wb[(r-194)*D_HM + col];
    else              v = 0.f;
    wcb[i] = f2bf(v);
  }
}

// ---------------------------------------------------------------- GEMM1: Y = [in|h|m] @ W_h^T  (pre-LN, f32)
// 128x128 tile, BK=32, 4 waves, all-LDS-direct (bf16 sources). Each BK chunk
// lies in exactly one source (boundaries 512/1536 are /32). Mapping bm=blk&127:
// same-bm blocks are 128 apart -> same XCD -> A panel fetched once per L2.
__global__ __launch_bounds__(256, 2) void gemm1(
    const unsigned short* __restrict__ Xb,  // 16384 x 512
    const unsigned short* __restrict__ Hb,  // 16384 x 1024
    const unsigned short* __restrict__ Mb,  // 16384 x 1152
    const unsigned short* __restrict__ W,   // 1024 x 2688 bf16
    float* __restrict__ Y) {                // 16384 x 1024 f32
  __shared__ __align__(16) unsigned short As[128*32];
  __shared__ __align__(16) unsigned short Bs[128*32];
  const int tid  = threadIdx.x;
  const int lane = tid & 63;
  const int wave = tid >> 6;
  const int bm = blockIdx.x & 127;
  const int bn = blockIdx.x >> 7;
  const int wr = wave >> 1, wc = wave & 1;
  const int lr = lane & 15, kh = lane >> 4;

  f32x4 acc[4][4];
  #pragma unroll
  for (int i = 0; i < 4; ++i)
    #pragma unroll
    for (int j = 0; j < 4; ++j) acc[i][j] = (f32x4)(0.f);

  const unsigned short* Wbase = W + (size_t)(bn*128) * D_C;
  const int s0 = tid, s1 = tid + 256;
  const int ar0 = s0 >> 2, ac0 = (s0 & 3) * 8;
  const int ar1 = s1 >> 2, ac1 = (s1 & 3) * 8;

  for (int k0 = 0; k0 < D_C; k0 += 32) {
    const unsigned short* asrc; int ald, akk;
    if (k0 < 512)       { asrc = Xb; ald = D_IN;  akk = k0; }
    else if (k0 < 1536) { asrc = Hb; ald = D_HID; akk = k0 - 512; }
    else                { asrc = Mb; ald = D_MEM; akk = k0 - 1536; }
    GLOAD16(asrc + (size_t)(bm*128 + ar0)*ald + akk + ac0, As + s0*8);
    GLOAD16(asrc + (size_t)(bm*128 + ar1)*ald + akk + ac1, As + s1*8);
    GLOAD16(Wbase + (size_t)ar0*D_C + k0 + ac0, Bs + s0*8);
    GLOAD16(Wbase + (size_t)ar1*D_C + k0 + ac1, Bs + s1*8);
    __syncthreads();
    bf16x8 a[4], b[4];
    #pragma unroll
    for (int mi = 0; mi < 4; ++mi)
      a[mi] = *(const bf16x8*)(As + (wr*64 + mi*16 + lr)*32 + kh*8);
    #pragma unroll
    for (int ni = 0; ni < 4; ++ni)
      b[ni] = *(const bf16x8*)(Bs + (wc*64 + ni*16 + lr)*32 + kh*8);
    #pragma unroll
    for (int mi = 0; mi < 4; ++mi)
      #pragma unroll
      for (int ni = 0; ni < 4; ++ni)
        acc[mi][ni] = __builtin_amdgcn_mfma_f32_16x16x32_bf16(a[mi], b[ni], acc[mi][ni], 0, 0, 0);
    __syncthreads();
  }
  const int orow0 = bm*128 + wr*64;
  const int ocol0 = bn*128 + wc*64;
  #pragma unroll
  for (int mi = 0; mi < 4; ++mi)
    #pragma unroll
    for (int ni = 0; ni < 4; ++ni)
      #pragma unroll
      for (int i = 0; i < 4; ++i) {
        int r  = orow0 + mi*16 + kh*4 + i;     // C row = (lane>>4)*4 + reg
        int cc = ocol0 + ni*16 + lr;           // C col = lane&15
        Y[(size_t)r * D_HID + cc] = acc[mi][ni][i];
      }
}

// ---------------------------------------------------------------- LN + ReLU, wave-per-row (no block barrier)
__global__ __launch_bounds__(256) void ln_relu(
    float* __restrict__ Y, const float* __restrict__ bh,
    const float* __restrict__ g, const float* __restrict__ bb,
    unsigned short* __restrict__ hmh) {       // 16384 x 1024 bf16
  const int row  = blockIdx.x * 4 + (threadIdx.x >> 6);
  const int lane = threadIdx.x & 63;
  float4* Yrow = (float4*)(Y + (size_t)row * D_HID);
  const float4* bh4 = (const float4*)bh;
  float4 x[4];
  float s = 0.f, sq = 0.f;
  #pragma unroll
  for (int j = 0; j < 4; ++j) {
    float4 v = Yrow[lane + 64*j];
    float4 b4 = bh4[lane + 64*j];
    v.x += b4.x; v.y += b4.y; v.z += b4.z; v.w += b4.w;
    x[j] = v;
    s  += v.x + v.y + v.z + v.w;
    sq += v.x*v.x + v.y*v.y + v.z*v.z + v.w*v.w;
  }
  #pragma unroll
  for (int off = 32; off >= 1; off >>= 1) {
    s  += __shfl_xor(s,  off, 64);
    sq += __shfl_xor(sq, off, 64);
  }
  float mu   = s * (1.f/1024.f);
  float var  = sq * (1.f/1024.f) - mu*mu;
  float rstd = rsqrtf(var + 1e-5f);
  const float4* g4p  = (const float4*)g;
  const float4* bb4p = (const float4*)bb;
  ushort4* hrow = (ushort4*)(hmh + (size_t)row * D_HID);
  #pragma unroll
  for (int j = 0; j < 4; ++j) {
    float4 g4 = g4p[lane + 64*j], bb4 = bb4p[lane + 64*j];
    float4 o;
    o.x = fmaxf(0.f, (x[j].x - mu)*rstd*g4.x + bb4.x);
    o.y = fmaxf(0.f, (x[j].y - mu)*rstd*g4.y + bb4.y);
    o.z = fmaxf(0.f, (x[j].z - mu)*rstd*g4.z + bb4.z);
    o.w = fmaxf(0.f, (x[j].w - mu)*rstd*g4.w + bb4.w);
    Yrow[lane + 64*j] = o;
    ushort4 ob; ob.x=f2bf(o.x); ob.y=f2bf(o.y); ob.z=f2bf(o.z); ob.w=f2bf(o.w);
    hrow[lane + 64*j] = ob;
  }
}

// ---------------------------------------------------------------- GEMM2+gate fused
// 32x224 tile, BK=32, 4 waves (256 thr), grid 512 -> 2 blocks/CU overlap.
// Wave col split: {64,64,48,48} cols = {4,4,3,3} frags of 16. Rows: 2 groups of 16.
// Epilogue: factorized-5-norm gate from LDS: m = m_prev + u2a*qa - u2b*qb.
// LDS union: staging {bias 896 | As 2048 | Bs 14336} vs epilogue
//            {bias 896 | Us 28672 | sm 1024 | coef 512 | q 6144} -> 37248 B.
__global__ __launch_bounds__(256, 4) void gemm2g(
    const unsigned short* __restrict__ Hb,  // 16384 x 1024 bf16 (post-LN h)
    const unsigned short* __restrict__ Mb,  // 16384 x 1152 bf16 (m_prev)
    const unsigned short* __restrict__ W,   // 224 x 2176 bf16
    const float* __restrict__ ba, const float* __restrict__ bbt,
    const float* __restrict__ bva, const float* __restrict__ bvb,
    const float* __restrict__ mp,           // f32 m_prev
    float* __restrict__ Mo) {               // f32 m out
  __shared__ __align__(16) char smem[37248];
  float*          bias_s = (float*)smem;                         // 224 f32
  unsigned short* As     = (unsigned short*)(smem + 896);        // 32*32 bf16
  unsigned short* Bs     = (unsigned short*)(smem + 896 + 2048); // 224*32 bf16
  float*          Us     = (float*)(smem + 896);                 // 32*224 f32
  float*          sm_s   = (float*)(smem + 896 + 28672);         // 32*8
  float*          coef_s = (float*)(smem + 896 + 28672 + 1024);  // 32*4
  float*          q_s    = (float*)(smem + 896 + 28672 + 1536);  // 32*48

  const int tid  = threadIdx.x;
  const int lane = tid & 63;
  const int wave = tid >> 6;
  const int lr = lane & 15, kh = lane >> 4;
  const int bm = blockIdx.x;
  const int cs = (wave < 2) ? wave*64 : 128 + (wave-2)*48;
  const int nf = (wave < 2) ? 4 : 3;

  if (tid < N_U) {
    int c = tid; float v;
    if (c < 96)       v = bva[c];
    else if (c < 192) v = bvb[c - 96];
    else if (c < 194) v = ba[c - 192];
    else if (c < 196) v = bbt[c - 194];
    else              v = 0.f;
    bias_s[c] = v;
  }

  f32x4 acc[2][4];
  #pragma unroll
  for (int g = 0; g < 2; ++g)
    #pragma unroll
    for (int i = 0; i < 4; ++i) acc[g][i] = (f32x4)(0.f);

  for (int k0 = 0; k0 < D_HM; k0 += 32) {
    // ---- A tile (32 rows x 32): 128 slots of 16B
    if (tid < 128) {
      const unsigned short* asrc; int ald, akk;
      if (k0 < 1024) { asrc = Hb; ald = D_HID; akk = k0; }
      else           { asrc = Mb; ald = D_MEM; akk = k0 - 1024; }
      GLOAD16(asrc + (size_t)(bm*32 + (tid>>2))*ald + akk + (tid&3)*8, As + tid*8);
    }
    // ---- B tile: 896 slots of 16B
    #pragma unroll
    for (int kq = 0; kq < 3; ++kq) {
      int sb = tid + 256*kq;
      GLOAD16(W + (size_t)(sb>>2)*D_HM + k0 + (sb&3)*8, Bs + sb*8);
    }
    if (tid < 128) {
      int sb = tid + 768;
      GLOAD16(W + (size_t)(sb>>2)*D_HM + k0 + (sb&3)*8, Bs + sb*8);
    }
    __syncthreads();
    bf16x8 a0 = *(const bf16x8*)(As + (lr)*32 + kh*8);
    bf16x8 a1 = *(const bf16x8*)(As + (16 + lr)*32 + kh*8);
    #pragma unroll
    for (int ni = 0; ni < 4; ++ni) {
      if (ni < nf) {
        bf16x8 b = *(const bf16x8*)(Bs + (cs + ni*16 + lr)*32 + kh*8);
        acc[0][ni] = __builtin_amdgcn_mfma_f32_16x16x32_bf16(a0, b, acc[0][ni], 0, 0, 0);
        acc[1][ni] = __builtin_amdgcn_mfma_f32_16x16x32_bf16(a1, b, acc[1][ni], 0, 0, 0);
      }
    }
    __syncthreads();
  }

  // ---- (a) acc -> Us with bias (staging LDS now dead)
  #pragma unroll
  for (int ni = 0; ni < 4; ++ni) {
    if (ni < nf) {
      int cc = cs + ni*16 + lr;
      float bv = bias_s[cc];
      #pragma unroll
      for (int g = 0; g < 2; ++g) {
        int row = g*16 + kh*4;
        #pragma unroll
        for (int i = 0; i < 4; ++i)
          Us[(row + i)*N_U + cc] = acc[g][ni][i] + bv;
      }
    }
  }
  __syncthreads();

  const int gr = tid >> 3;     // row 0..31
  const int gj = tid & 7;      // 8 threads per row
  // ---- (b) segment partial sums of |su|^5: thread gj covers [gj*24, gj*24+24)
  {
    const float* su = Us + gr*N_U;
    float ssum = 0.f;
    #pragma unroll 4
    for (int i = 0; i < 24; ++i) {
      float a = fabsf(su[gj*24 + i]);
      float a2 = a*a;
      ssum += a2*a2*a;
    }
    sm_s[gr*8 + gj] = ssum;
  }
  __syncthreads();
  // ---- (c) coefs (one thread per row)
  if (gj == 0) {
    const float* sm = sm_s + gr*8;
    const float* su = Us + gr*N_U;
    float S2a = sm[2] + sm[3];       // sum |u2a|^5
    float S2b = sm[6] + sm[7];       // sum |u2b|^5
    float n0 = powf(sm[0]*S2a, 0.2f);
    float n1 = powf(sm[1]*S2a, 0.2f);
    float n2 = powf(sm[4]*S2b, 0.2f);
    float n3 = powf(sm[5]*S2b, 0.2f);
    coef_s[gr*4+0] = 0.5f * su[192] / fmaxf(n0, 1e-12f);
    coef_s[gr*4+1] = 0.5f * su[193] / fmaxf(n1, 1e-12f);
    coef_s[gr*4+2] = 0.5f * su[194] / fmaxf(n2, 1e-12f);
    coef_s[gr*4+3] = 0.5f * su[195] / fmaxf(n3, 1e-12f);
  }
  __syncthreads();
  // ---- (d) q vectors: 48 per row, 6 per thread
  {
    const float* su = Us + gr*N_U;
    const float* cf = coef_s + gr*4;
    #pragma unroll
    for (int i = 0; i < 6; ++i) {
      int mq = gj*6 + i;
      float v;
      if (mq < 24) v = cf[0]*su[mq]         + cf[1]*su[24 + mq];
      else         v = cf[2]*su[96 + mq-24] + cf[3]*su[120 + mq-24];
      q_s[gr*48 + mq] = v;
    }
  }
  __syncthreads();
  // ---- (e) m = m_prev + u2a*qa - u2b*qb   (32 rows x 1152)
  {
    const float4* mp4 = (const float4*)(mp + (size_t)(bm*32) * D_MEM);
    float4*       mo4 = (float4*)(Mo + (size_t)(bm*32) * D_MEM);
    for (int idx = tid; idx < 32*288; idx += 256) {
      int row = idx / 288;
      int p4  = idx - row*288;
      int p = p4*4;
      int rr = p/48, c = p - rr*48;    // c multiple of 4
      const float* su = Us + row*N_U;
      float A0 = q_s[row*48 + rr], B0 = q_s[row*48 + 24 + rr];
      float4 m = mp4[row*288 + p4];
      float4 o;
      o.x = m.x + su[48 + c    ]*A0 - su[144 + c    ]*B0;
      o.y = m.y + su[48 + c + 1]*A0 - su[144 + c + 1]*B0;
      o.z = m.z + su[48 + c + 2]*A0 - su[144 + c + 2]*B0;
      o.w = m.w + su[48 + c + 3]*A0 - su[144 + c + 3]*B0;
      mo4[row*288 + p4] = o;
    }
  }
}

// ---------------------------------------------------------------- launch
extern "C" void kernel_launch(void* const* d_in, const int* in_sizes, int n_in,
                              void* d_out, int out_size, void* d_ws, size_t ws_size,
                              hipStream_t stream) {
  const float* input  = (const float*)d_in[0];
  const float* h_prev = (const float*)d_in[1];
  const float* m_prev = (const float*)d_in[2];
  const float* W_h    = (const float*)d_in[3];
  const float* b_h    = (const float*)d_in[4];
  const float* ln_g   = (const float*)d_in[5];
  const float* ln_b   = (const float*)d_in[6];
  const float* W_a    = (const float*)d_in[7];
  const float* b_a    = (const float*)d_in[8];
  const float* W_b    = (const float*)d_in[9];
  const float* b_b    = (const float*)d_in[10];
  const float* W_va   = (const float*)d_in[11];
  const float* b_va   = (const float*)d_in[12];
  const float* W_vb   = (const float*)d_in[13];
  const float* b_vb   = (const float*)d_in[14];

  const size_t off_wh   = 0;
  const size_t off_wcat = off_wh   + (size_t)D_HID * D_C * 2;       //  5,505,024
  const size_t off_xb   = off_wcat + (size_t)N_U * D_HM * 2;        //  6,479,872
  const size_t off_hb   = off_xb   + (size_t)B_ROWS * D_IN * 2;     // 23,257,088
  const size_t off_mb   = off_hb   + (size_t)B_ROWS * D_HID * 2;    // 56,811,520
  const size_t off_hmh  = off_mb   + (size_t)B_ROWS * D_MEM * 2;    // 94,560,256
  const size_t need     = off_hmh  + (size_t)B_ROWS * D_HID * 2;    // 128,114,688
  if (ws_size < need) return;

  char* ws = (char*)d_ws;
  unsigned short* wh_bf = (unsigned short*)(ws + off_wh);
  unsigned short* wc_bf = (unsigned short*)(ws + off_wcat);
  unsigned short* xb    = (unsigned short*)(ws + off_xb);
  unsigned short* hb    = (unsigned short*)(ws + off_hb);
  unsigned short* mb    = (unsigned short*)(ws + off_mb);
  unsigned short* hmh   = (unsigned short*)(ws + off_hmh);

  float* h_out = (float*)d_out;                     // B x 1024
  float* m_out = h_out + (size_t)B_ROWS * D_HID;    // B x 1152

  prep   <<<2048, 256, 0, stream>>>(input, h_prev, m_prev, W_h,
                                    W_va, W_vb, W_a, W_b,
                                    xb, hb, mb, wh_bf, wc_bf);
  gemm1  <<<1024, 256, 0, stream>>>(xb, hb, mb, wh_bf, h_out);
  ln_relu<<<B_ROWS / 4, 256, 0, stream>>>(h_out, b_h, ln_g, ln_b, hmh);
  gemm2g <<<B_ROWS / 32, 256, 0, stream>>>(hmh, mb, wc_bf, b_a, b_b, b_va, b_vb, m_prev, m_out);
}